// Round 1
// 778.577 us; speedup vs baseline: 1.0653x; 1.0653x over previous
//
#include <hip/hip_runtime.h>
#include <stdint.h>

#define L48   48
#define NLOC  2304      // 48*48
#define C3CH  256
#define KDIM  2304      // 256*9
#define BATCH 4
#define PADLOC 2400     // 50 rows * 48

typedef _Float16 half8 __attribute__((ext_vector_type(8)));
typedef float    floatx4 __attribute__((ext_vector_type(4)));
typedef unsigned short ushort8v __attribute__((ext_vector_type(8)));

union H16 { _Float16 f; unsigned short u; };

// ---------------- norms: one wave per patch location (unchanged) ----------------
__global__ __launch_bounds__(256) void norm_kernel(const float* __restrict__ img,
                                                   float* __restrict__ inv_norm)
{
    int wid  = (blockIdx.x * 256 + threadIdx.x) >> 6;
    int lane = threadIdx.x & 63;
    if (wid >= BATCH * NLOC) return;
    int b = wid / NLOC;
    int m = wid - b * NLOC;
    int y = m / L48, x = m - y * L48;
    const float* base = img + (size_t)b * C3CH * NLOC;
    float acc = 0.f;
    for (int e = lane; e < KDIM; e += 64) {
        int c = e / 9;
        int r = e - c * 9;
        int yy = y + r / 3 - 1;
        int xx = x + (r % 3) - 1;
        float v = 0.f;
        if ((unsigned)yy < 48u && (unsigned)xx < 48u)
            v = base[c * NLOC + yy * L48 + xx];
        acc += v * v;
    }
    #pragma unroll
    for (int off = 32; off >= 1; off >>= 1)
        acc += __shfl_xor(acc, off, 64);
    if (lane == 0) {
        float n = fmaxf(sqrtf(acc), 1e-12f);
        inv_norm[wid] = 1.f / n;
    }
}

// ---------------- prep: fp32 image -> K-major granule split-fp16 ----------------
// New global layout (per array): plane p = ox*4+b in [0,12):
//   element layout: [p][G=0..31][loc=0..2399] of ushort8 granules (16 B),
//   granule (p,G,loc) = channels 8G..8G+7 at padded location loc (= yy*48+x,
//   value img[c][yy-1][x+ox-1], 0 if OOB).
// This is exactly the order search_mfma streams into LDS via global_load_lds.
__global__ __launch_bounds__(256) void prep_kernel(const float* __restrict__ img,
                                                   unsigned short* __restrict__ out_hi,
                                                   unsigned short* __restrict__ out_lo)
{
    __shared__ unsigned short hi[256 * 50];
    __shared__ unsigned short lo[256 * 50];
    int bid = blockIdx.x;
    int oxIdx = bid / 200;
    int rem   = bid % 200;
    int b     = rem / 50;
    int yy    = rem % 50;
    int kj = oxIdx - 1;
    int y  = yy - 1;
    int t = threadIdx.x;
    bool yok = (unsigned)y < 48u;
    const float* ibase = img + (size_t)b * C3CH * NLOC;
    for (int flat = t; flat < 256 * 48; flat += 256) {
        int c = flat / 48;
        int x = flat - c * 48;
        int xs = x + kj;
        float v = 0.f;
        if (yok && (unsigned)xs < 48u)
            v = ibase[c * NLOC + y * L48 + xs];
        H16 h, l;
        h.f = (_Float16)v;
        float rvv = (v - (float)h.f) * 2048.0f;
        l.f = (_Float16)rvv;
        hi[c * 50 + x] = h.u;
        lo[c * 50 + x] = l.u;
    }
    __syncthreads();
    size_t plane = (size_t)(oxIdx * 4 + b);
    for (int flat = t; flat < 32 * 48; flat += 256) {
        int G = flat / 48;
        int x = flat - G * 48;
        ushort8v vh, vl;
        #pragma unroll
        for (int j = 0; j < 8; ++j) {
            vh[j] = hi[(G * 8 + j) * 50 + x];
            vl[j] = lo[(G * 8 + j) * 50 + x];
        }
        size_t o8 = ((plane * 32 + G) * PADLOC + (size_t)yy * 48 + x) * 8;
        *(ushort8v*)(out_hi + o8) = vh;
        *(ushort8v*)(out_lo + o8) = vl;
    }
}

// ---------------- search: fp16 hi/lo split MFMA GEMM, fused argmax ----------------
// LDS per buffer per array: 512 granules of 16B = 8 KB, laid out K-major:
//   granule index g = q*128 + r  (q = k-granule 0..3 of the 32-ch chunk, r = row 0..127)
// Fragment read by 16 consecutive lanes = 256 B contiguous -> conflict-free.
// Staging: global_load_lds dwordx4, linear dest, 1 KB/wave, perfectly coalesced.

__device__ __forceinline__ void stage_arr(const unsigned short* __restrict__ gbase, // + (plane*32+cc*4)*PADLOC*8
                                          int loc0,
                                          unsigned short* lbase,
                                          int wv, int lane)
{
    #pragma unroll
    for (int j = 0; j < 2; ++j) {
        int bg = (j * 4 + wv) * 64;          // base granule in [0,512)
        int q  = bg >> 7;
        int r0 = bg & 127;
        const unsigned short* gp = gbase + ((size_t)q * PADLOC + loc0 + r0 + lane) * 8;
        unsigned short* lp = lbase + (size_t)(bg + lane) * 8;
        __builtin_amdgcn_global_load_lds((const __attribute__((address_space(1))) void*)gp,
                                         (__attribute__((address_space(3))) void*)lp,
                                         16, 0, 0);
    }
}

__global__ __launch_bounds__(256, 2) void search_mfma(const unsigned short* __restrict__ At_hi,
                                                      const unsigned short* __restrict__ At_lo,
                                                      const unsigned short* __restrict__ Bt_hi,
                                                      const unsigned short* __restrict__ Bt_lo,
                                                      const float* __restrict__ nr_inv,
                                                      unsigned long long* __restrict__ packed)
{
    // 2 buffers x 4 arrays x 4096 ushorts (8KB) = 65536 B
    __shared__ __align__(16) unsigned short lds[2 * 4 * 4096];

    const int tid = threadIdx.x;
    const int b  = blockIdx.z;
    const int l0 = blockIdx.y * 128;
    const int m0 = blockIdx.x * 128;

    const int lane = tid & 63;
    const int wv = tid >> 6;          // wave id 0..3
    const int wr = tid >> 7;          // wave row 0..1
    const int wc = (tid >> 6) & 1;    // wave col 0..1
    const int mrow = lane & 15;
    const int q = lane >> 4;          // k-granule 0..3

    floatx4 acc1[4][4];
    floatx4 acc2[4][4];
    #pragma unroll
    for (int i = 0; i < 4; ++i)
        #pragma unroll
        for (int j = 0; j < 4; ++j) { acc1[i][j] = (floatx4)0.f; acc2[i][j] = (floatx4)0.f; }

    auto issue = [&](int it, int sel) {
        int o  = it >> 3;
        int cc = it & 7;
        int od3 = o / 3;
        int ki  = od3 - 1;
        int ox  = o - od3 * 3;
        int plane = ox * 4 + b;
        int locA = l0 + 48 * (1 + ki);
        int locB = m0 + 48 * (1 + ki);
        size_t gb = (size_t)(plane * 32 + cc * 4) * (PADLOC * 8);
        unsigned short* L = (unsigned short*)lds + sel * 16384;
        stage_arr(At_hi + gb, locA, L,         wv, lane);
        stage_arr(At_lo + gb, locA, L + 4096,  wv, lane);
        stage_arr(Bt_hi + gb, locB, L + 8192,  wv, lane);
        stage_arr(Bt_lo + gb, locB, L + 12288, wv, lane);
    };

    issue(0, 0);
    __syncthreads();   // drains vmcnt(0): buffer 0 ready

    for (int it = 0; it < 72; ++it) {
        const int sel = it & 1;
        if (it + 1 < 72) issue(it + 1, sel ^ 1);   // async prefetch overlaps this iter's compute

        const _Float16* L  = (const _Float16*)((unsigned short*)lds + sel * 16384);
        const _Float16* Ah = L;
        const _Float16* Al = L + 4096;
        const _Float16* Bh = L + 8192;
        const _Float16* Bl = L + 12288;

        half8 ahf[4], alf[4];
        #pragma unroll
        for (int fi = 0; fi < 4; ++fi) {
            int g = q * 128 + wr * 64 + fi * 16 + mrow;
            ahf[fi] = *(const half8*)(Ah + g * 8);
            alf[fi] = *(const half8*)(Al + g * 8);
        }
        #pragma unroll
        for (int fj = 0; fj < 4; ++fj) {
            int g = q * 128 + wc * 64 + fj * 16 + mrow;
            half8 bhf = *(const half8*)(Bh + g * 8);
            half8 blf = *(const half8*)(Bl + g * 8);
            #pragma unroll
            for (int fi = 0; fi < 4; ++fi) {
                acc1[fi][fj] = __builtin_amdgcn_mfma_f32_16x16x32_f16(ahf[fi], bhf, acc1[fi][fj], 0, 0, 0);
                acc2[fi][fj] = __builtin_amdgcn_mfma_f32_16x16x32_f16(ahf[fi], blf, acc2[fi][fj], 0, 0, 0);
                acc2[fi][fj] = __builtin_amdgcn_mfma_f32_16x16x32_f16(alf[fi], bhf, acc2[fi][fj], 0, 0, 0);
            }
        }
        __syncthreads();   // drains prefetch vmcnt + separates read of buf[sel] from its overwrite
    }

    // ---- epilogue: row-normalize, per-column argmax over l within block ----
    float* redv = (float*)lds;               // [8][128]
    int*   redi = (int*)(redv + 8 * 128);    // [8][128]

    const float inv2048 = 1.0f / 2048.0f;
    float bestv[4];
    int   besti[4];
    #pragma unroll
    for (int fj = 0; fj < 4; ++fj) { bestv[fj] = -1e30f; besti[fj] = 0; }

    #pragma unroll
    for (int fi = 0; fi < 4; ++fi) {
        int rowbase = l0 + wr * 64 + fi * 16 + (lane >> 4) * 4;
        #pragma unroll
        for (int r = 0; r < 4; ++r) {
            float rinv = nr_inv[b * NLOC + rowbase + r];
            #pragma unroll
            for (int fj = 0; fj < 4; ++fj) {
                float v = (acc1[fi][fj][r] + acc2[fi][fj][r] * inv2048) * rinv;
                if (v > bestv[fj]) { bestv[fj] = v; besti[fj] = rowbase + r; }
            }
        }
    }

    int cand = wr * 4 + (lane >> 4);   // 0..7
    #pragma unroll
    for (int fj = 0; fj < 4; ++fj) {
        int col = wc * 64 + fj * 16 + mrow;
        redv[cand * 128 + col] = bestv[fj];
        redi[cand * 128 + col] = besti[fj];
    }
    __syncthreads();
    if (tid < 128) {
        float best = redv[tid];
        int   bi   = redi[tid];
        #pragma unroll
        for (int c = 1; c < 8; ++c) {
            float v  = redv[c * 128 + tid];
            int   i2 = redi[c * 128 + tid];
            if (v > best || (v == best && i2 < bi)) { best = v; bi = i2; }
        }
        unsigned int sv = __float_as_uint(best);
        sv = (sv & 0x80000000u) ? ~sv : (sv | 0x80000000u);
        unsigned long long p = ((unsigned long long)sv << 32)
                             | (unsigned long long)(0xFFFFFFFFu - (unsigned)bi);
        atomicMax(packed + b * NLOC + m0 + tid, p);
    }
}

// ---------------- finalize: unpack S and argmax (unchanged) ----------------
__global__ __launch_bounds__(256) void finalize_kernel(const unsigned long long* __restrict__ packed,
                                                       const float* __restrict__ nl_inv,
                                                       float* __restrict__ S,
                                                       int* __restrict__ Rarg)
{
    int i = blockIdx.x * 256 + threadIdx.x;
    if (i >= BATCH * NLOC) return;
    unsigned long long p = packed[i];
    unsigned int sv   = (unsigned int)(p >> 32);
    unsigned int bits = (sv & 0x80000000u) ? (sv & 0x7FFFFFFFu) : ~sv;
    float val = __uint_as_float(bits);
    int   idx = (int)(0xFFFFFFFFu - (unsigned int)(p & 0xFFFFFFFFu));
    S[i]    = val * nl_inv[i];
    Rarg[i] = idx;
}

// ------------- transfer: fused gather + fold (unchanged) -------------
template<int C, int H, int K, int S, int P>
__global__ __launch_bounds__(256) void transfer_kernel(const float* __restrict__ ref,
                                                       const int* __restrict__ Rarg,
                                                       float* __restrict__ out)
{
    int idx = blockIdx.x * 256 + threadIdx.x;
    if (idx >= BATCH * C * H * H) return;
    int x = idx % H;
    int y = (idx / H) % H;
    int c = (idx / (H * H)) % C;
    int b = idx / (H * H * C);
    int Y = y + P, X = x + P;
    int ylo = Y - K + 1; ylo = (ylo > 0) ? (ylo + S - 1) / S : 0;
    int yhi = Y / S; if (yhi > 47) yhi = 47;
    int xlo = X - K + 1; xlo = (xlo > 0) ? (xlo + S - 1) / S : 0;
    int xhi = X / S; if (xhi > 47) xhi = 47;
    const float* rbase = ref + ((size_t)b * C + c) * H * H;
    const int*   abase = Rarg + b * NLOC;
    float acc = 0.f;
    for (int py = ylo; py <= yhi; ++py) {
        int ki = Y - py * S;
        for (int px = xlo; px <= xhi; ++px) {
            int kj = X - px * S;
            int q  = abase[py * L48 + px];
            int qy = q / L48, qx = q - qy * L48;
            int row = qy * S + ki - P;
            int col = qx * S + kj - P;
            if ((unsigned)row < (unsigned)H && (unsigned)col < (unsigned)H)
                acc += rbase[row * H + col];
        }
    }
    out[idx] = acc * (1.f / 9.f);
}

extern "C" void kernel_launch(void* const* d_in, const int* in_sizes, int n_in,
                              void* d_out, int out_size, void* d_ws, size_t ws_size,
                              hipStream_t stream)
{
    const float* lrsr  = (const float*)d_in[0];
    const float* refsr = (const float*)d_in[1];
    const float* ref1  = (const float*)d_in[2];
    const float* ref2  = (const float*)d_in[3];
    const float* ref3  = (const float*)d_in[4];

    float* S_out  = (float*)d_out;                   // 9216
    float* T3_out = S_out  + BATCH * NLOC;           // 2359296
    float* T2_out = T3_out + BATCH * 256 * 48 * 48;  // 4718592
    float* T1_out = T2_out + BATCH * 128 * 96 * 96;  // 9437184

    char* ws = (char*)d_ws;
    unsigned long long* packed = (unsigned long long*)ws;         // 73728 B
    float* nr_inv = (float*)(ws + 73728);                         // 36864 B
    float* nl_inv = (float*)(ws + 110592);                        // 36864 B
    int*   Rarg   = (int*)(ws + 147456);                          // 36864 B
    const size_t TSZ = (size_t)3 * BATCH * PADLOC * 256;          // 7372800 elements
    unsigned short* A_hi = (unsigned short*)(ws + 184320);
    unsigned short* A_lo = A_hi + TSZ;
    unsigned short* B_hi = A_lo + TSZ;
    unsigned short* B_lo = B_hi + TSZ;

    hipMemsetAsync(packed, 0, BATCH * NLOC * sizeof(unsigned long long), stream);
    norm_kernel<<<dim3(BATCH * NLOC / 4), 256, 0, stream>>>(refsr, nr_inv);
    norm_kernel<<<dim3(BATCH * NLOC / 4), 256, 0, stream>>>(lrsr,  nl_inv);
    prep_kernel<<<dim3(600), 256, 0, stream>>>(refsr, A_hi, A_lo);
    prep_kernel<<<dim3(600), 256, 0, stream>>>(lrsr,  B_hi, B_lo);

    search_mfma<<<dim3(18, 18, BATCH), 256, 0, stream>>>(A_hi, A_lo, B_hi, B_lo, nr_inv, packed);

    finalize_kernel<<<dim3(36), 256, 0, stream>>>(packed, nl_inv, S_out, Rarg);

    transfer_kernel<256,  48,  3, 1, 1><<<dim3(BATCH*256*48*48   / 256), 256, 0, stream>>>(ref3, Rarg, T3_out);
    transfer_kernel<128,  96,  6, 2, 2><<<dim3(BATCH*128*96*96   / 256), 256, 0, stream>>>(ref2, Rarg, T2_out);
    transfer_kernel< 64, 192, 12, 4, 4><<<dim3(BATCH*64*192*192  / 256), 256, 0, stream>>>(ref1, Rarg, T1_out);
}